// Round 12
// baseline (170.053 us; speedup 1.0000x reference)
//
#include <hip/hip_runtime.h>

// ---------------------------------------------------------------------------
// MultiHeadAttention (B=2, E=512, H=8, T=2048, DH=64), fp32 in/out.
//   K1 pre:   z<6: x[b][i][t]*mask -> xT bf16 ; z==6: weight-standardize -> bf16
//   K2 proj:  Y = Wn @ xT^T + bias, per-head LN fused (parallel stats);
//             BK=128, 16-chunk XOR swizzle. Q bf16 (scaled log2e/181), K bf16,
//             V -> Vf f16 in exact PV-MFMA B-fragment order (+mask row).
//   K3 attn:  register-softmax flash attention, q-tile 32, depth-2 chunk
//             pipeline, ~165 unified regs -> 3 waves/SIMD. Grid (bh, q0):
//             id%8 = bh%8 keeps each head's K/Vf on one XCD.
//   K4 oproj: out = WnO @ xa^T + bo -> fp32; BK=128.
// ---------------------------------------------------------------------------

typedef __bf16 bf16;
typedef __bf16 bf16x2 __attribute__((ext_vector_type(2)));
typedef __bf16 bf16x8 __attribute__((ext_vector_type(8)));
typedef _Float16 f16;
typedef _Float16 f16x8 __attribute__((ext_vector_type(8)));
typedef float  f32x4  __attribute__((ext_vector_type(4)));

#define MFMA_BF16(a, b, c) __builtin_amdgcn_mfma_f32_16x16x32_bf16((a), (b), (c), 0, 0, 0)
#define MFMA_F16_K32(a, b, c) __builtin_amdgcn_mfma_f32_16x16x32_f16((a), (b), (c), 0, 0, 0)

#if __has_builtin(__builtin_amdgcn_exp2f)
#define EXP2F(x) __builtin_amdgcn_exp2f(x)
#else
#define EXP2F(x) __expf((x) * 0.6931471805599453f)
#endif

#define NB   2
#define NE   512
#define NH   8
#define NT   2048
#define NDH  64
#define VF_BH_STRIDE (64 * 5 * 64 * 8)   // halfs per (b,h) in Vf

__device__ __forceinline__ void gl_lds16(const bf16* g, bf16* l) {
  __builtin_amdgcn_global_load_lds(
      (const __attribute__((address_space(1))) void*)g,
      (__attribute__((address_space(3))) void*)l, 16, 0, 0);
}

// ---------------- K1: fused transpose (z<6) + weight-standardize (z==6) ----
__global__ __launch_bounds__(256) void k_pre(
    const float* __restrict__ q, const float* __restrict__ k,
    const float* __restrict__ v,
    const int* __restrict__ qm, const int* __restrict__ km,
    const int* __restrict__ vm,
    const float* __restrict__ Wq, const float* __restrict__ Wk,
    const float* __restrict__ Wv, const float* __restrict__ Wo,
    bf16* __restrict__ xT, bf16* __restrict__ Wn)
{
  __shared__ float tile[64][65];
  int tid = threadIdx.x;
  if (blockIdx.z == 6) {
    int id = blockIdx.y * 32 + blockIdx.x;
    int w = tid >> 6, lane = tid & 63;
#pragma unroll
    for (int r = 0; r < 2; r++) {
      int rg  = id * 8 + w * 2 + r;            // 0..2047
      int mat = rg >> 9, row = rg & 511;
      const float* W = mat == 0 ? Wq : mat == 1 ? Wk : mat == 2 ? Wv : Wo;
      const float4* p = (const float4*)(W + row * NE) + lane * 2;
      float4 a = p[0], c = p[1];
      float s  = a.x + a.y + a.z + a.w + c.x + c.y + c.z + c.w;
      float ss = a.x*a.x + a.y*a.y + a.z*a.z + a.w*a.w
               + c.x*c.x + c.y*c.y + c.z*c.z + c.w*c.w;
#pragma unroll
      for (int m = 1; m < 64; m <<= 1) { s += __shfl_xor(s, m); ss += __shfl_xor(ss, m); }
      float mean = s * (1.0f / NE);
      float var  = ss * (1.0f / NE) - mean * mean;
      float rstd = rsqrtf(var + 1e-5f);
      bf16x8 o;
      o[0] = (bf16)((a.x - mean) * rstd); o[1] = (bf16)((a.y - mean) * rstd);
      o[2] = (bf16)((a.z - mean) * rstd); o[3] = (bf16)((a.w - mean) * rstd);
      o[4] = (bf16)((c.x - mean) * rstd); o[5] = (bf16)((c.y - mean) * rstd);
      o[6] = (bf16)((c.z - mean) * rstd); o[7] = (bf16)((c.w - mean) * rstd);
      *(bf16x8*)(Wn + (size_t)rg * NE + lane * 8) = o;
    }
    return;
  }
  int src = blockIdx.z >> 1, b = blockIdx.z & 1;
  const float* x = src == 0 ? q : src == 1 ? k : v;
  const int*   m = src == 0 ? qm : src == 1 ? km : vm;
  x += (size_t)b * NE * NT;
  m += b * NT;
  int t0 = blockIdx.x * 64, i0 = blockIdx.y * 64;
  int lr = tid >> 4, tc = (tid & 15) * 4;
#pragma unroll
  for (int p = 0; p < 4; p++) {
    int row = p * 16 + lr;
    float4 v4 = *(const float4*)(x + (size_t)(i0 + row) * NT + t0 + tc);
    tile[row][tc]     = v4.x; tile[row][tc + 1] = v4.y;
    tile[row][tc + 2] = v4.z; tile[row][tc + 3] = v4.w;
  }
  __syncthreads();
  bf16* o = xT + ((size_t)src * NB + b) * NT * NE;
  int i2 = (tid & 31) * 2, t2 = tid >> 5;
#pragma unroll
  for (int t = t2; t < 64; t += 8) {
    float mk = (float)m[t0 + t];
    bf16x2 w2;
    w2[0] = (bf16)(tile[i2][t] * mk);
    w2[1] = (bf16)(tile[i2 + 1][t] * mk);
    *(bf16x2*)(o + (size_t)(t0 + t) * NE + i0 + i2) = w2;
  }
}

// ---------------- K2: projection GEMM (BK=128) + fused per-head LN ---------
__global__ __launch_bounds__(256) void k_proj(
    const bf16* __restrict__ Wn,   // [3+1][512][512]
    const bf16* __restrict__ xT,   // [3][B][T][E]
    const int* __restrict__ km,    // key_mask
    const float* __restrict__ bq, const float* __restrict__ bk,
    const float* __restrict__ bv,
    const float* __restrict__ gq, const float* __restrict__ bbq,
    const float* __restrict__ gk, const float* __restrict__ bbk,
    const float* __restrict__ gv, const float* __restrict__ bbv,
    bf16* __restrict__ Qh, bf16* __restrict__ Kh, f16* __restrict__ Vf)
{
  int src = blockIdx.z >> 1, b = blockIdx.z & 1;
  const bf16* A  = Wn + src * (NE * NE);
  const bf16* Bm = xT + ((size_t)src * NB + b) * NT * NE;
  int m0 = blockIdx.y * 64, n0 = blockIdx.x * 128;
  int h = m0 >> 6;

  __shared__ __align__(16) char smem[49152];
  bf16*  Al = (bf16*)smem;            // [64][128] swizzled (16 KB)
  bf16*  Bl = (bf16*)(smem + 16384);  // [128][128] swizzled (32 KB)
  float* Yl = (float*)smem;           // [64][130] overlay (33280 B)
  float* mu = (float*)(smem + 33280);
  float* rs = (float*)(smem + 33792);
  float* ps = (float*)(smem + 34304); // [2][128] partial sums
  float* pq = (float*)(smem + 35328); // [2][128] partial sumsq

  int tid = threadIdx.x, lane = tid & 63, w = tid >> 6;
  int mh = (w & 1) * 32, nh = (w >> 1) * 64;
  int lr4 = lane >> 4, c16 = lane & 15;
  f32x4 acc[2][4] = {};

  for (int k0 = 0; k0 < NE; k0 += 128) {
    __syncthreads();
#pragma unroll
    for (int i = 0; i < 4; i++) {   // A: 64 rows x 256B
      int row = w * 16 + i * 4 + lr4;
      gl_lds16(A + (m0 + row) * NE + k0 + ((c16 ^ (row & 15)) << 3),
               Al + (w * 16 + i * 4) * 128);
    }
#pragma unroll
    for (int i = 0; i < 8; i++) {   // B: 128 rows x 256B
      int row = w * 32 + i * 4 + lr4;
      gl_lds16(Bm + (size_t)(n0 + row) * NE + k0 + ((c16 ^ (row & 15)) << 3),
               Bl + (w * 32 + i * 4) * 128);
    }
    __syncthreads();
#pragma unroll
    for (int kk = 0; kk < 128; kk += 32) {
      bf16x8 af[2], bfv[4];
#pragma unroll
      for (int ms = 0; ms < 2; ms++) {
        int row = mh + ms * 16 + (lane & 15);
        int slot = ((kk >> 3) + (lane >> 4)) ^ (row & 15);
        af[ms] = *(const bf16x8*)(Al + row * 128 + (slot << 3));
      }
#pragma unroll
      for (int ns = 0; ns < 4; ns++) {
        int row = nh + ns * 16 + (lane & 15);
        int slot = ((kk >> 3) + (lane >> 4)) ^ (row & 15);
        bfv[ns] = *(const bf16x8*)(Bl + row * 128 + (slot << 3));
      }
#pragma unroll
      for (int ms = 0; ms < 2; ms++)
#pragma unroll
        for (int ns = 0; ns < 4; ns++)
          acc[ms][ns] = MFMA_BF16(af[ms], bfv[ns], acc[ms][ns]);
    }
  }

  __syncthreads();
  {
    const float* bias = src == 0 ? bq : src == 1 ? bk : bv;
#pragma unroll
    for (int ms = 0; ms < 2; ms++)
#pragma unroll
      for (int ns = 0; ns < 4; ns++)
#pragma unroll
        for (int r = 0; r < 4; r++) {
          int om = mh + ms * 16 + ((lane >> 4) << 2) + r;
          int on = nh + ns * 16 + (lane & 15);
          Yl[om * 130 + on] = acc[ms][ns][r] + bias[m0 + om];
        }
  }
  __syncthreads();
  {  // parallel LN stats: 256 threads, each col half; then 2-way combine
    int c = tid & 127, hh = tid >> 7;
    float s = 0.f, ss = 0.f;
#pragma unroll 8
    for (int o = hh * 32; o < hh * 32 + 32; o++) {
      float y = Yl[o * 130 + c]; s += y; ss += y * y;
    }
    ps[hh * 128 + c] = s; pq[hh * 128 + c] = ss;
  }
  __syncthreads();
  if (tid < 128) {
    float s  = ps[tid] + ps[128 + tid];
    float ss = pq[tid] + pq[128 + tid];
    float mean = s * (1.0f / 64.0f);
    float var  = ss * (1.0f / 64.0f) - mean * mean;
    mu[tid] = mean;
    rs[tid] = rsqrtf(var + 1e-5f);
  }
  __syncthreads();

  if (src < 2) {
    float scl = (src == 0) ? (1.4426950408889634f / 181.0f) : 1.0f;
    const float* g  = src == 0 ? gq  : gk;
    const float* bb = src == 0 ? bbq : bbk;
    bf16* out = (src == 0 ? Qh : Kh) + ((size_t)(b * NH + h) * NT + n0) * NDH;
    int d2 = (tid & 31) * 2, tb2 = tid >> 5;
    float g0 = g[d2] * scl,     b0 = bb[d2] * scl;
    float g1 = g[d2 + 1] * scl, b1 = bb[d2 + 1] * scl;
#pragma unroll
    for (int t = tb2; t < 128; t += 8) {
      float rmu = mu[t], rrs = rs[t];
      bf16x2 w2;
      w2[0] = (bf16)((Yl[d2 * 130 + t] - rmu) * rrs * g0 + b0);
      w2[1] = (bf16)((Yl[(d2 + 1) * 130 + t] - rmu) * rrs * g1 + b1);
      *(bf16x2*)(out + (size_t)t * NDH + d2) = w2;
    }
  } else {
    // V -> PV B-fragment order Vf[bh][g][j5][lane][8]; masked cols zeroed.
    int gl = tid >> 6, lane2 = tid & 63;
    int quad2 = lane2 >> 4, l15b = lane2 & 15;
    int bh = b * NH + h;
    f16* base = Vf + (size_t)bh * VF_BH_STRIDE
              + (size_t)((n0 >> 5) + gl) * (5 * 64 * 8) + lane2 * 8;
    int   tl[8]; float mk[8];
#pragma unroll
    for (int j = 0; j < 8; j++) {
      tl[j] = gl * 32 + ((j < 4) ? quad2 * 4 + j : 16 + quad2 * 4 + (j - 4));
      mk[j] = (float)km[b * NT + n0 + tl[j]];
    }
#pragma unroll
    for (int ds = 0; ds < 4; ds++) {
      int d = ds * 16 + l15b;
      float gg = gv[d], bb3 = bbv[d];
      f16x8 o;
#pragma unroll
      for (int j = 0; j < 8; j++) {
        int t = tl[j];
        o[j] = (f16)(((Yl[d * 130 + t] - mu[t]) * rs[t] * gg + bb3) * mk[j]);
      }
      *(f16x8*)(base + ds * (64 * 8)) = o;
    }
    f16x8 om;
#pragma unroll
    for (int j = 0; j < 8; j++) om[j] = (f16)mk[j];
    *(f16x8*)(base + 4 * (64 * 8)) = om;
  }
}

// ---------------- K3: flash attention v12 (q-tile 32, 3 waves/SIMD) --------
// grid (bh=16, qt=64), block 256 = 4 waves; wave w owns keys [w*32,+32) of
// each 128-key tile, all 32 q. Depth-2 register pipeline. Per-wave unified
// regs ~165 -> 3 waves/SIMD (vs 2 at q-tile 64) for better latency hiding.
struct KV {
  bf16x8 ka[2][2];   // [kt][hf] A-operand of QK^T (m=key)
  f16x8  vb[5];      // [j5] fragment-order V (0..3) + mask (4)
};

__device__ __forceinline__ void kv_load(KV& s, const bf16* Kb, const f16* VfW,
                                        int kk) {
#pragma unroll
  for (int kt = 0; kt < 2; kt++)
#pragma unroll
    for (int hf = 0; hf < 2; hf++)
      s.ka[kt][hf] = *(const bf16x8*)(Kb + (size_t)(kk + kt * 16) * NDH + hf * 32);
  const f16* vp = VfW + (size_t)(kk >> 5) * (5 * 512);
#pragma unroll
  for (int j5 = 0; j5 < 5; j5++)
    s.vb[j5] = *(const f16x8*)(vp + j5 * 512);
}

__device__ __forceinline__ void kv_comp(const KV& s, const bf16x8 qb[2][2],
                                        f32x4 acco[2][4], f32x4 dacc[2]) {
#pragma unroll
  for (int qs = 0; qs < 2; qs++) {
    f32x4 z0 = {}, z1 = {};
    z0 = MFMA_BF16(s.ka[0][0], qb[qs][0], z0);
    z0 = MFMA_BF16(s.ka[0][1], qb[qs][1], z0);
    z1 = MFMA_BF16(s.ka[1][0], qb[qs][0], z1);
    z1 = MFMA_BF16(s.ka[1][1], qb[qs][1], z1);
    f16x8 pa;
#pragma unroll
    for (int r = 0; r < 4; r++) {
      pa[r]     = (f16)EXP2F(z0[r]);
      pa[4 + r] = (f16)EXP2F(z1[r]);
    }
    dacc[qs] = MFMA_F16_K32(pa, s.vb[4], dacc[qs]);
#pragma unroll
    for (int ds = 0; ds < 4; ds++)
      acco[qs][ds] = MFMA_F16_K32(pa, s.vb[ds], acco[qs][ds]);
  }
}

__global__ __launch_bounds__(256) void k_attn(
    const bf16* __restrict__ Qh, const bf16* __restrict__ Kh,
    const f16* __restrict__ Vf, const int* __restrict__ qmask,
    bf16* __restrict__ xa)  // [B][T][E]
{
  int bh = blockIdx.x, b = bh >> 3, h = bh & 7;   // XCD = bh%8
  int q0 = blockIdx.y * 32;
  const bf16* Q = Qh + (size_t)bh * NT * NDH;
  const bf16* K = Kh + (size_t)bh * NT * NDH;
  const f16*  VfB = Vf + (size_t)bh * VF_BH_STRIDE;

  __shared__ __align__(16) char smem[2 * 32 * 68 * 4 + 4 * 32 * 4]; // 17920 B
  float* OlA  = (float*)smem;                     // [32][68]
  float* OlB  = (float*)(smem + 32 * 68 * 4);     // [32][68]
  float* denl = (float*)(smem + 2 * 32 * 68 * 4); // [4][32]

  int tid = threadIdx.x, lane = tid & 63, w = tid >> 6;
  int quad = lane >> 4, l15 = lane & 15;
  const int ko = w * 32;

  bf16x8 qb[2][2];
#pragma unroll
  for (int qs = 0; qs < 2; qs++)
#pragma unroll
    for (int hf = 0; hf < 2; hf++)
      qb[qs][hf] = *(const bf16x8*)(Q + (size_t)(q0 + qs * 16 + l15) * NDH + hf * 32 + quad * 8);

  const bf16* Kb  = K + (size_t)(ko + l15) * NDH + quad * 8;
  const f16*  VfW = VfB + (size_t)w * (5 * 512) + lane * 8;

  f32x4 acco[2][4] = {};
  f32x4 dacc[2]    = {};

  // depth-2 chunk pipeline: 16 chunks of 32 keys; load chunk c+2 while
  // computing chunk c.
  KV s0, s1;
  kv_load(s0, Kb, VfW, 0);
  kv_load(s1, Kb, VfW, 128);

#pragma unroll
  for (int c = 0; c < 16; c++) {
    KV n;
    if (c < 14) kv_load(n, Kb, VfW, c * 128 + 256);
    kv_comp(s0, qb, acco, dacc);
    s0 = s1; s1 = n;   // renamed away under full unroll
  }

  if (l15 == 0)
#pragma unroll
    for (int qs = 0; qs < 2; qs++)
#pragma unroll
      for (int r = 0; r < 4; r++)
        denl[w * 32 + qs * 16 + quad * 4 + r] = dacc[qs][r];

  float* Obuf = (w < 2) ? OlA : OlB;
  if ((w & 1) == 0) {
#pragma unroll
    for (int qs = 0; qs < 2; qs++)
#pragma unroll
      for (int ds = 0; ds < 4; ds++)
#pragma unroll
        for (int r = 0; r < 4; r++)
          Obuf[(qs * 16 + quad * 4 + r) * 68 + ds * 16 + l15] = acco[qs][ds][r];
  }
  __syncthreads();
  if (w & 1) {
#pragma unroll
    for (int qs = 0; qs < 2; qs++)
#pragma unroll
      for (int ds = 0; ds < 4; ds++)
#pragma unroll
        for (int r = 0; r < 4; r++)
          Obuf[(qs * 16 + quad * 4 + r) * 68 + ds * 16 + l15] += acco[qs][ds][r];
  }
  __syncthreads();

#pragma unroll
  for (int i = 0; i < 8; i++) {
    int ql = w * 8 + i;
    float dtot = denl[ql] + denl[32 + ql] + denl[64 + ql] + denl[96 + ql];
    float qm = (float)qmask[b * NT + q0 + ql];
    float inv = qm / dtot;   // masked query -> exact 0
    float val = (OlA[ql * 68 + lane] + OlB[ql * 68 + lane]) * inv;
    xa[((size_t)b * NT + q0 + ql) * NE + h * NDH + lane] = (bf16)val;
  }
}

// ---------------- K4: output projection (64x64 tiles, BK=128) --------------
__global__ __launch_bounds__(256) void k_oproj(
    const bf16* __restrict__ A,    // WnO [512][512]
    const bf16* __restrict__ xab,  // [B][T][E]
    const float* __restrict__ bo, float* __restrict__ out)
{
  int b = blockIdx.z;
  const bf16* Bm = xab + (size_t)b * NT * NE;
  int m0 = blockIdx.y * 64, n0 = blockIdx.x * 64;

  __shared__ __align__(16) char smem[32768];
  bf16* Al = (bf16*)smem;            // [64][128] swizzled
  bf16* Bl = (bf16*)(smem + 16384);  // [64][128] swizzled

  int tid = threadIdx.x, lane = tid & 63, w = tid >> 6;
  int mh = (w & 1) * 32, nh = (w >> 1) * 32;
  int lr4 = lane >> 4, c16 = lane & 15;
  f32x4 acc[2][2] = {};

  for (int k0 = 0; k0 < NE; k0 += 128) {
    __syncthreads();
#pragma unroll
    for (int i = 0; i < 4; i++) {
      int row = w * 16 + i * 4 + lr4;
      gl_lds16(A + (m0 + row) * NE + k0 + ((c16 ^ (row & 15)) << 3),
               Al + (w * 16 + i * 4) * 128);
    }
#pragma unroll
    for (int i = 0; i < 4; i++) {
      int row = w * 16 + i * 4 + lr4;
      gl_lds16(Bm + (size_t)(n0 + row) * NE + k0 + ((c16 ^ (row & 15)) << 3),
               Bl + (w * 16 + i * 4) * 128);
    }
    __syncthreads();
#pragma unroll
    for (int kk = 0; kk < 128; kk += 32) {
      bf16x8 af[2], bfv[2];
#pragma unroll
      for (int ms = 0; ms < 2; ms++) {
        int row = mh + ms * 16 + (lane & 15);
        int slot = ((kk >> 3) + (lane >> 4)) ^ (row & 15);
        af[ms] = *(const bf16x8*)(Al + row * 128 + (slot << 3));
      }
#pragma unroll
      for (int ns = 0; ns < 2; ns++) {
        int row = nh + ns * 16 + (lane & 15);
        int slot = ((kk >> 3) + (lane >> 4)) ^ (row & 15);
        bfv[ns] = *(const bf16x8*)(Bl + row * 128 + (slot << 3));
      }
#pragma unroll
      for (int ms = 0; ms < 2; ms++)
#pragma unroll
        for (int ns = 0; ns < 2; ns++)
          acc[ms][ns] = MFMA_BF16(af[ms], bfv[ns], acc[ms][ns]);
    }
  }

#pragma unroll
  for (int ms = 0; ms < 2; ms++)
#pragma unroll
    for (int ns = 0; ns < 2; ns++)
#pragma unroll
      for (int r = 0; r < 4; r++) {
        int o = m0 + mh + ms * 16 + ((lane >> 4) << 2) + r;
        int t = n0 + nh + ns * 16 + (lane & 15);
        out[(size_t)b * NE * NT + (size_t)o * NT + t] = acc[ms][ns][r] + bo[o];
      }
}

// ---------------------------------------------------------------------------
extern "C" void kernel_launch(void* const* d_in, const int* in_sizes, int n_in,
                              void* d_out, int out_size, void* d_ws, size_t ws_size,
                              hipStream_t stream)
{
  const float* q  = (const float*)d_in[0];
  const float* k  = (const float*)d_in[1];
  const float* v  = (const float*)d_in[2];
  const int*   qm = (const int*)d_in[3];
  const int*   km = (const int*)d_in[4];
  const int*   vm = (const int*)d_in[5];
  const float* Wq = (const float*)d_in[6];  const float* bq = (const float*)d_in[7];
  const float* Wk = (const float*)d_in[8];  const float* bk = (const float*)d_in[9];
  const float* Wv = (const float*)d_in[10]; const float* bv = (const float*)d_in[11];
  const float* Wo = (const float*)d_in[12]; const float* bo = (const float*)d_in[13];
  const float* gq = (const float*)d_in[14]; const float* bbq = (const float*)d_in[15];
  const float* gk = (const float*)d_in[16]; const float* bbk = (const float*)d_in[17];
  const float* gv = (const float*)d_in[18]; const float* bbv = (const float*)d_in[19];
  float* out = (float*)d_out;

  char* wsb = (char*)d_ws;
  bf16*  Wn  = (bf16*)(wsb);                        //  2 MiB: 4x[512][512]
  bf16*  xT  = (bf16*)(wsb + (2ull  << 20));        // 12 MiB (dead after proj)
  bf16*  xa  = (bf16*)(wsb + (2ull  << 20));        //  4 MiB (reuses dead xT)
  bf16*  Qh  = (bf16*)(wsb + (14ull << 20));        //  4 MiB: [B][H][T][DH]
  bf16*  Kh  = (bf16*)(wsb + (18ull << 20));        //  4 MiB
  f16*   Vf  = (f16*) (wsb + (22ull << 20));        //  5.25 MiB: fragment-order V+mask

  k_pre  <<<dim3(32, 8, 7), 256, 0, stream>>>(q, k, v, qm, km, vm,
                                              Wq, Wk, Wv, Wo, xT, Wn);
  k_proj <<<dim3(16, 8, 6), 256, 0, stream>>>(Wn, xT, km, bq, bk, bv,
                                              gq, bbq, gk, bbk, gv, bbv,
                                              Qh, Kh, Vf);
  k_attn <<<dim3(16, 64),   256, 0, stream>>>(Qh, Kh, Vf, qm, xa);
  k_oproj<<<dim3(32, 8, 2), 256, 0, stream>>>(Wn + 3 * NE * NE, xa, bo, out);
}

// Round 13
// 156.308 us; speedup vs baseline: 1.0879x; 1.0879x over previous
//
#include <hip/hip_runtime.h>

// ---------------------------------------------------------------------------
// MultiHeadAttention (B=2, E=512, H=8, T=2048, DH=64), fp32 in/out.
//   K1 pre:   z<6: x[b][i][t]*mask -> xT bf16 ; z==6: weight-standardize -> bf16
//   K2 proj:  Y = Wn @ xT^T + bias, per-head LN fused (parallel stats);
//             BK=128, 16-chunk XOR swizzle. Q bf16 (scaled log2e/181), K bf16,
//             V -> Vf f16 in exact PV-MFMA B-fragment order (+mask row).
//   K3 attn:  register-softmax flash attention, q-tile 64, depth-3 chunk
//             pipeline. Grid (bh, q0): id%8 = bh%8 keeps each head's K/Vf on
//             one XCD (FETCH 40->11 MB measured).
//   K4 oproj: out = WnO @ xa^T + bo -> fp32; BK=128.
// Best-measured configuration (R10 core + R11 grid): ~156.5 us.
// ---------------------------------------------------------------------------

typedef __bf16 bf16;
typedef __bf16 bf16x2 __attribute__((ext_vector_type(2)));
typedef __bf16 bf16x8 __attribute__((ext_vector_type(8)));
typedef _Float16 f16;
typedef _Float16 f16x8 __attribute__((ext_vector_type(8)));
typedef float  f32x4  __attribute__((ext_vector_type(4)));

#define MFMA_BF16(a, b, c) __builtin_amdgcn_mfma_f32_16x16x32_bf16((a), (b), (c), 0, 0, 0)
#define MFMA_F16_K32(a, b, c) __builtin_amdgcn_mfma_f32_16x16x32_f16((a), (b), (c), 0, 0, 0)

#if __has_builtin(__builtin_amdgcn_exp2f)
#define EXP2F(x) __builtin_amdgcn_exp2f(x)
#else
#define EXP2F(x) __expf((x) * 0.6931471805599453f)
#endif

#define NB   2
#define NE   512
#define NH   8
#define NT   2048
#define NDH  64
#define VF_BH_STRIDE (64 * 5 * 64 * 8)   // halfs per (b,h) in Vf

__device__ __forceinline__ void gl_lds16(const bf16* g, bf16* l) {
  __builtin_amdgcn_global_load_lds(
      (const __attribute__((address_space(1))) void*)g,
      (__attribute__((address_space(3))) void*)l, 16, 0, 0);
}

// ---------------- K1: fused transpose (z<6) + weight-standardize (z==6) ----
__global__ __launch_bounds__(256) void k_pre(
    const float* __restrict__ q, const float* __restrict__ k,
    const float* __restrict__ v,
    const int* __restrict__ qm, const int* __restrict__ km,
    const int* __restrict__ vm,
    const float* __restrict__ Wq, const float* __restrict__ Wk,
    const float* __restrict__ Wv, const float* __restrict__ Wo,
    bf16* __restrict__ xT, bf16* __restrict__ Wn)
{
  __shared__ float tile[64][65];
  int tid = threadIdx.x;
  if (blockIdx.z == 6) {
    // weight standardization: 256 blocks x 8 rows (2 rows/wave)
    int id = blockIdx.y * 32 + blockIdx.x;
    int w = tid >> 6, lane = tid & 63;
#pragma unroll
    for (int r = 0; r < 2; r++) {
      int rg  = id * 8 + w * 2 + r;            // 0..2047
      int mat = rg >> 9, row = rg & 511;
      const float* W = mat == 0 ? Wq : mat == 1 ? Wk : mat == 2 ? Wv : Wo;
      const float4* p = (const float4*)(W + row * NE) + lane * 2;
      float4 a = p[0], c = p[1];
      float s  = a.x + a.y + a.z + a.w + c.x + c.y + c.z + c.w;
      float ss = a.x*a.x + a.y*a.y + a.z*a.z + a.w*a.w
               + c.x*c.x + c.y*c.y + c.z*c.z + c.w*c.w;
#pragma unroll
      for (int m = 1; m < 64; m <<= 1) { s += __shfl_xor(s, m); ss += __shfl_xor(ss, m); }
      float mean = s * (1.0f / NE);
      float var  = ss * (1.0f / NE) - mean * mean;
      float rstd = rsqrtf(var + 1e-5f);
      bf16x8 o;
      o[0] = (bf16)((a.x - mean) * rstd); o[1] = (bf16)((a.y - mean) * rstd);
      o[2] = (bf16)((a.z - mean) * rstd); o[3] = (bf16)((a.w - mean) * rstd);
      o[4] = (bf16)((c.x - mean) * rstd); o[5] = (bf16)((c.y - mean) * rstd);
      o[6] = (bf16)((c.z - mean) * rstd); o[7] = (bf16)((c.w - mean) * rstd);
      *(bf16x8*)(Wn + (size_t)rg * NE + lane * 8) = o;
    }
    return;
  }
  int src = blockIdx.z >> 1, b = blockIdx.z & 1;
  const float* x = src == 0 ? q : src == 1 ? k : v;
  const int*   m = src == 0 ? qm : src == 1 ? km : vm;
  x += (size_t)b * NE * NT;
  m += b * NT;
  int t0 = blockIdx.x * 64, i0 = blockIdx.y * 64;
  int lr = tid >> 4, tc = (tid & 15) * 4;
#pragma unroll
  for (int p = 0; p < 4; p++) {
    int row = p * 16 + lr;
    float4 v4 = *(const float4*)(x + (size_t)(i0 + row) * NT + t0 + tc);
    tile[row][tc]     = v4.x; tile[row][tc + 1] = v4.y;
    tile[row][tc + 2] = v4.z; tile[row][tc + 3] = v4.w;
  }
  __syncthreads();
  bf16* o = xT + ((size_t)src * NB + b) * NT * NE;
  int i2 = (tid & 31) * 2, t2 = tid >> 5;
#pragma unroll
  for (int t = t2; t < 64; t += 8) {
    float mk = (float)m[t0 + t];
    bf16x2 w2;
    w2[0] = (bf16)(tile[i2][t] * mk);
    w2[1] = (bf16)(tile[i2 + 1][t] * mk);
    *(bf16x2*)(o + (size_t)(t0 + t) * NE + i0 + i2) = w2;
  }
}

// ---------------- K2: projection GEMM (BK=128) + fused per-head LN ---------
__global__ __launch_bounds__(256) void k_proj(
    const bf16* __restrict__ Wn,   // [3+1][512][512]
    const bf16* __restrict__ xT,   // [3][B][T][E]
    const int* __restrict__ km,    // key_mask
    const float* __restrict__ bq, const float* __restrict__ bk,
    const float* __restrict__ bv,
    const float* __restrict__ gq, const float* __restrict__ bbq,
    const float* __restrict__ gk, const float* __restrict__ bbk,
    const float* __restrict__ gv, const float* __restrict__ bbv,
    bf16* __restrict__ Qh, bf16* __restrict__ Kh, f16* __restrict__ Vf)
{
  int src = blockIdx.z >> 1, b = blockIdx.z & 1;
  const bf16* A  = Wn + src * (NE * NE);
  const bf16* Bm = xT + ((size_t)src * NB + b) * NT * NE;
  int m0 = blockIdx.y * 64, n0 = blockIdx.x * 128;
  int h = m0 >> 6;

  __shared__ __align__(16) char smem[49152];
  bf16*  Al = (bf16*)smem;            // [64][128] swizzled (16 KB)
  bf16*  Bl = (bf16*)(smem + 16384);  // [128][128] swizzled (32 KB)
  float* Yl = (float*)smem;           // [64][130] overlay (33280 B)
  float* mu = (float*)(smem + 33280);
  float* rs = (float*)(smem + 33792);
  float* ps = (float*)(smem + 34304); // [2][128] partial sums
  float* pq = (float*)(smem + 35328); // [2][128] partial sumsq

  int tid = threadIdx.x, lane = tid & 63, w = tid >> 6;
  int mh = (w & 1) * 32, nh = (w >> 1) * 64;
  int lr4 = lane >> 4, c16 = lane & 15;
  f32x4 acc[2][4] = {};

  for (int k0 = 0; k0 < NE; k0 += 128) {
    __syncthreads();
#pragma unroll
    for (int i = 0; i < 4; i++) {   // A: 64 rows x 256B
      int row = w * 16 + i * 4 + lr4;
      gl_lds16(A + (m0 + row) * NE + k0 + ((c16 ^ (row & 15)) << 3),
               Al + (w * 16 + i * 4) * 128);
    }
#pragma unroll
    for (int i = 0; i < 8; i++) {   // B: 128 rows x 256B
      int row = w * 32 + i * 4 + lr4;
      gl_lds16(Bm + (size_t)(n0 + row) * NE + k0 + ((c16 ^ (row & 15)) << 3),
               Bl + (w * 32 + i * 4) * 128);
    }
    __syncthreads();
#pragma unroll
    for (int kk = 0; kk < 128; kk += 32) {
      bf16x8 af[2], bfv[4];
#pragma unroll
      for (int ms = 0; ms < 2; ms++) {
        int row = mh + ms * 16 + (lane & 15);
        int slot = ((kk >> 3) + (lane >> 4)) ^ (row & 15);
        af[ms] = *(const bf16x8*)(Al + row * 128 + (slot << 3));
      }
#pragma unroll
      for (int ns = 0; ns < 4; ns++) {
        int row = nh + ns * 16 + (lane & 15);
        int slot = ((kk >> 3) + (lane >> 4)) ^ (row & 15);
        bfv[ns] = *(const bf16x8*)(Bl + row * 128 + (slot << 3));
      }
#pragma unroll
      for (int ms = 0; ms < 2; ms++)
#pragma unroll
        for (int ns = 0; ns < 4; ns++)
          acc[ms][ns] = MFMA_BF16(af[ms], bfv[ns], acc[ms][ns]);
    }
  }

  __syncthreads();
  {
    const float* bias = src == 0 ? bq : src == 1 ? bk : bv;
#pragma unroll
    for (int ms = 0; ms < 2; ms++)
#pragma unroll
      for (int ns = 0; ns < 4; ns++)
#pragma unroll
        for (int r = 0; r < 4; r++) {
          int om = mh + ms * 16 + ((lane >> 4) << 2) + r;
          int on = nh + ns * 16 + (lane & 15);
          Yl[om * 130 + on] = acc[ms][ns][r] + bias[m0 + om];
        }
  }
  __syncthreads();
  {  // parallel LN stats: 256 threads, each col half; then 2-way combine
    int c = tid & 127, hh = tid >> 7;
    float s = 0.f, ss = 0.f;
#pragma unroll 8
    for (int o = hh * 32; o < hh * 32 + 32; o++) {
      float y = Yl[o * 130 + c]; s += y; ss += y * y;
    }
    ps[hh * 128 + c] = s; pq[hh * 128 + c] = ss;
  }
  __syncthreads();
  if (tid < 128) {
    float s  = ps[tid] + ps[128 + tid];
    float ss = pq[tid] + pq[128 + tid];
    float mean = s * (1.0f / 64.0f);
    float var  = ss * (1.0f / 64.0f) - mean * mean;
    mu[tid] = mean;
    rs[tid] = rsqrtf(var + 1e-5f);
  }
  __syncthreads();

  if (src < 2) {
    float scl = (src == 0) ? (1.4426950408889634f / 181.0f) : 1.0f;
    const float* g  = src == 0 ? gq  : gk;
    const float* bb = src == 0 ? bbq : bbk;
    bf16* out = (src == 0 ? Qh : Kh) + ((size_t)(b * NH + h) * NT + n0) * NDH;
    int d2 = (tid & 31) * 2, tb2 = tid >> 5;
    float g0 = g[d2] * scl,     b0 = bb[d2] * scl;
    float g1 = g[d2 + 1] * scl, b1 = bb[d2 + 1] * scl;
#pragma unroll
    for (int t = tb2; t < 128; t += 8) {
      float rmu = mu[t], rrs = rs[t];
      bf16x2 w2;
      w2[0] = (bf16)((Yl[d2 * 130 + t] - rmu) * rrs * g0 + b0);
      w2[1] = (bf16)((Yl[(d2 + 1) * 130 + t] - rmu) * rrs * g1 + b1);
      *(bf16x2*)(out + (size_t)t * NDH + d2) = w2;
    }
  } else {
    // V -> PV B-fragment order Vf[bh][g][j5][lane][8]; masked cols zeroed.
    int gl = tid >> 6, lane2 = tid & 63;
    int quad2 = lane2 >> 4, l15b = lane2 & 15;
    int bh = b * NH + h;
    f16* base = Vf + (size_t)bh * VF_BH_STRIDE
              + (size_t)((n0 >> 5) + gl) * (5 * 64 * 8) + lane2 * 8;
    int   tl[8]; float mk[8];
#pragma unroll
    for (int j = 0; j < 8; j++) {
      tl[j] = gl * 32 + ((j < 4) ? quad2 * 4 + j : 16 + quad2 * 4 + (j - 4));
      mk[j] = (float)km[b * NT + n0 + tl[j]];
    }
#pragma unroll
    for (int ds = 0; ds < 4; ds++) {
      int d = ds * 16 + l15b;
      float gg = gv[d], bb3 = bbv[d];
      f16x8 o;
#pragma unroll
      for (int j = 0; j < 8; j++) {
        int t = tl[j];
        o[j] = (f16)(((Yl[d * 130 + t] - mu[t]) * rs[t] * gg + bb3) * mk[j]);
      }
      *(f16x8*)(base + ds * (64 * 8)) = o;
    }
    f16x8 om;
#pragma unroll
    for (int j = 0; j < 8; j++) om[j] = (f16)mk[j];
    *(f16x8*)(base + 4 * (64 * 8)) = om;
  }
}

// ---------------- K3: flash attention (q-tile 64, depth-3, XCD-local) ------
struct KV {
  bf16x8 ka[2][2];   // [kt][hf] A-operand of QK^T (m=key)
  f16x8  vb[5];      // [j5] fragment-order V (0..3) + mask (4)
};

__device__ __forceinline__ void kv_load(KV& s, const bf16* Kb, const f16* VfW,
                                        int kk) {
#pragma unroll
  for (int kt = 0; kt < 2; kt++)
#pragma unroll
    for (int hf = 0; hf < 2; hf++)
      s.ka[kt][hf] = *(const bf16x8*)(Kb + (size_t)(kk + kt * 16) * NDH + hf * 32);
  const f16* vp = VfW + (size_t)(kk >> 5) * (5 * 512);
#pragma unroll
  for (int j5 = 0; j5 < 5; j5++)
    s.vb[j5] = *(const f16x8*)(vp + j5 * 512);
}

__device__ __forceinline__ void kv_comp(const KV& s, const bf16x8 qb[4][2],
                                        f32x4 acco[4][4], f32x4 dacc[4]) {
#pragma unroll
  for (int qs = 0; qs < 4; qs++) {
    f32x4 z0 = {}, z1 = {};
    z0 = MFMA_BF16(s.ka[0][0], qb[qs][0], z0);
    z0 = MFMA_BF16(s.ka[0][1], qb[qs][1], z0);
    z1 = MFMA_BF16(s.ka[1][0], qb[qs][0], z1);
    z1 = MFMA_BF16(s.ka[1][1], qb[qs][1], z1);
    f16x8 pa;
#pragma unroll
    for (int r = 0; r < 4; r++) {
      pa[r]     = (f16)EXP2F(z0[r]);
      pa[4 + r] = (f16)EXP2F(z1[r]);
    }
    dacc[qs] = MFMA_F16_K32(pa, s.vb[4], dacc[qs]);
#pragma unroll
    for (int ds = 0; ds < 4; ds++)
      acco[qs][ds] = MFMA_F16_K32(pa, s.vb[ds], acco[qs][ds]);
  }
}

__global__ __launch_bounds__(256) void k_attn(
    const bf16* __restrict__ Qh, const bf16* __restrict__ Kh,
    const f16* __restrict__ Vf, const int* __restrict__ qmask,
    bf16* __restrict__ xa)  // [B][T][E]
{
  int bh = blockIdx.x, b = bh >> 3, h = bh & 7;   // XCD = bh%8
  int q0 = blockIdx.y * 64;
  const bf16* Q = Qh + (size_t)bh * NT * NDH;
  const bf16* K = Kh + (size_t)bh * NT * NDH;
  const f16*  VfB = Vf + (size_t)bh * VF_BH_STRIDE;

  __shared__ __align__(16) char smem[2 * 64 * 68 * 4 + 4 * 64 * 4]; // 35840 B
  float* OlA  = (float*)smem;                     // [64][68]
  float* OlB  = (float*)(smem + 64 * 68 * 4);     // [64][68]
  float* denl = (float*)(smem + 2 * 64 * 68 * 4); // [4][64]

  int tid = threadIdx.x, lane = tid & 63, w = tid >> 6;
  int quad = lane >> 4, l15 = lane & 15;
  const int ko = w * 32;

  bf16x8 qb[4][2];
#pragma unroll
  for (int qs = 0; qs < 4; qs++)
#pragma unroll
    for (int hf = 0; hf < 2; hf++)
      qb[qs][hf] = *(const bf16x8*)(Q + (size_t)(q0 + qs * 16 + l15) * NDH + hf * 32 + quad * 8);

  const bf16* Kb  = K + (size_t)(ko + l15) * NDH + quad * 8;
  const f16*  VfW = VfB + (size_t)w * (5 * 512) + lane * 8;

  f32x4 acco[4][4] = {};
  f32x4 dacc[4]    = {};

  // depth-3 chunk pipeline: 16 chunks of 32 keys; load chunk c+3 while
  // computing chunk c.
  KV s0, s1, s2;
  kv_load(s0, Kb, VfW, 0);
  kv_load(s1, Kb, VfW, 128);
  kv_load(s2, Kb, VfW, 256);

#pragma unroll
  for (int c = 0; c < 16; c++) {
    KV n;
    if (c < 13) kv_load(n, Kb, VfW, c * 128 + 384);
    kv_comp(s0, qb, acco, dacc);
    s0 = s1; s1 = s2; s2 = n;   // renamed away under full unroll
  }

  if (l15 == 0)
#pragma unroll
    for (int qs = 0; qs < 4; qs++)
#pragma unroll
      for (int r = 0; r < 4; r++)
        denl[w * 64 + qs * 16 + quad * 4 + r] = dacc[qs][r];

  float* Obuf = (w < 2) ? OlA : OlB;
  if ((w & 1) == 0) {
#pragma unroll
    for (int qs = 0; qs < 4; qs++)
#pragma unroll
      for (int ds = 0; ds < 4; ds++)
#pragma unroll
        for (int r = 0; r < 4; r++)
          Obuf[(qs * 16 + quad * 4 + r) * 68 + ds * 16 + l15] = acco[qs][ds][r];
  }
  __syncthreads();
  if (w & 1) {
#pragma unroll
    for (int qs = 0; qs < 4; qs++)
#pragma unroll
      for (int ds = 0; ds < 4; ds++)
#pragma unroll
        for (int r = 0; r < 4; r++)
          Obuf[(qs * 16 + quad * 4 + r) * 68 + ds * 16 + l15] += acco[qs][ds][r];
  }
  __syncthreads();

#pragma unroll
  for (int i = 0; i < 16; i++) {
    int ql = w * 16 + i;
    float dtot = denl[ql] + denl[64 + ql] + denl[128 + ql] + denl[192 + ql];
    float qm = (float)qmask[b * NT + q0 + ql];
    float inv = qm / dtot;   // masked query -> exact 0
    float val = (OlA[ql * 68 + lane] + OlB[ql * 68 + lane]) * inv;
    xa[((size_t)b * NT + q0 + ql) * NE + h * NDH + lane] = (bf16)val;
  }
}

// ---------------- K4: output projection (64x64 tiles, BK=128) --------------
__global__ __launch_bounds__(256) void k_oproj(
    const bf16* __restrict__ A,    // WnO [512][512]
    const bf16* __restrict__ xab,  // [B][T][E]
    const float* __restrict__ bo, float* __restrict__ out)
{
  int b = blockIdx.z;
  const bf16* Bm = xab + (size_t)b * NT * NE;
  int m0 = blockIdx.y * 64, n0 = blockIdx.x * 64;

  __shared__ __align__(16) char smem[32768];
  bf16* Al = (bf16*)smem;            // [64][128] swizzled
  bf16* Bl = (bf16*)(smem + 16384);  // [64][128] swizzled

  int tid = threadIdx.x, lane = tid & 63, w = tid >> 6;
  int mh = (w & 1) * 32, nh = (w >> 1) * 32;
  int lr4 = lane >> 4, c16 = lane & 15;
  f32x4 acc[2][2] = {};

  for (int k0 = 0; k0 < NE; k0 += 128) {
    __syncthreads();
#pragma unroll
    for (int i = 0; i < 4; i++) {
      int row = w * 16 + i * 4 + lr4;
      gl_lds16(A + (m0 + row) * NE + k0 + ((c16 ^ (row & 15)) << 3),
               Al + (w * 16 + i * 4) * 128);
    }
#pragma unroll
    for (int i = 0; i < 4; i++) {
      int row = w * 16 + i * 4 + lr4;
      gl_lds16(Bm + (size_t)(n0 + row) * NE + k0 + ((c16 ^ (row & 15)) << 3),
               Bl + (w * 16 + i * 4) * 128);
    }
    __syncthreads();
#pragma unroll
    for (int kk = 0; kk < 128; kk += 32) {
      bf16x8 af[2], bfv[2];
#pragma unroll
      for (int ms = 0; ms < 2; ms++) {
        int row = mh + ms * 16 + (lane & 15);
        int slot = ((kk >> 3) + (lane >> 4)) ^ (row & 15);
        af[ms] = *(const bf16x8*)(Al + row * 128 + (slot << 3));
      }
#pragma unroll
      for (int ns = 0; ns < 2; ns++) {
        int row = nh + ns * 16 + (lane & 15);
        int slot = ((kk >> 3) + (lane >> 4)) ^ (row & 15);
        bfv[ns] = *(const bf16x8*)(Bl + row * 128 + (slot << 3));
      }
#pragma unroll
      for (int ms = 0; ms < 2; ms++)
#pragma unroll
        for (int ns = 0; ns < 2; ns++)
          acc[ms][ns] = MFMA_BF16(af[ms], bfv[ns], acc[ms][ns]);
    }
  }

#pragma unroll
  for (int ms = 0; ms < 2; ms++)
#pragma unroll
    for (int ns = 0; ns < 2; ns++)
#pragma unroll
      for (int r = 0; r < 4; r++) {
        int o = m0 + mh + ms * 16 + ((lane >> 4) << 2) + r;
        int t = n0 + nh + ns * 16 + (lane & 15);
        out[(size_t)b * NE * NT + (size_t)o * NT + t] = acc[ms][ns][r] + bo[o];
      }
}

// ---------------------------------------------------------------------------
extern "C" void kernel_launch(void* const* d_in, const int* in_sizes, int n_in,
                              void* d_out, int out_size, void* d_ws, size_t ws_size,
                              hipStream_t stream)
{
  const float* q  = (const float*)d_in[0];
  const float* k  = (const float*)d_in[1];
  const float* v  = (const float*)d_in[2];
  const int*   qm = (const int*)d_in[3];
  const int*   km = (const int*)d_in[4];
  const int*   vm = (const int*)d_in[5];
  const float* Wq = (const float*)d_in[6];  const float* bq = (const float*)d_in[7];
  const float* Wk = (const float*)d_in[8];  const float* bk = (const float*)d_in[9];
  const float* Wv = (const float*)d_in[10]; const float* bv = (const float*)d_in[11];
  const float* Wo = (const float*)d_in[12]; const float* bo = (const float*)d_in[13];
  const float* gq = (const float*)d_in[14]; const float* bbq = (const float*)d_in[15];
  const float* gk = (const float*)d_in[16]; const float* bbk = (const float*)d_in[17];
  const float* gv = (const float*)d_in[18]; const float* bbv = (const float*)d_in[19];
  float* out = (float*)d_out;

  char* wsb = (char*)d_ws;
  bf16*  Wn  = (bf16*)(wsb);                        //  2 MiB: 4x[512][512]
  bf16*  xT  = (bf16*)(wsb + (2ull  << 20));        // 12 MiB (dead after proj)
  bf16*  xa  = (bf16*)(wsb + (2ull  << 20));        //  4 MiB (reuses dead xT)
  bf16*  Qh  = (bf16*)(wsb + (14ull << 20));        //  4 MiB: [B][H][T][DH]
  bf16*  Kh  = (bf16*)(wsb + (18ull << 20));        //  4 MiB
  f16*   Vf  = (f16*) (wsb + (22ull << 20));        //  5.25 MiB: fragment-order V+mask

  k_pre  <<<dim3(32, 8, 7), 256, 0, stream>>>(q, k, v, qm, km, vm,
                                              Wq, Wk, Wv, Wo, xT, Wn);
  k_proj <<<dim3(16, 8, 6), 256, 0, stream>>>(Wn, xT, km, bq, bk, bv,
                                              gq, bbq, gk, bbk, gv, bbv,
                                              Qh, Kh, Vf);
  k_attn <<<dim3(16, 32),   256, 0, stream>>>(Qh, Kh, Vf, qm, xa);
  k_oproj<<<dim3(32, 8, 2), 256, 0, stream>>>(Wn + 3 * NE * NE, xa, bo, out);
}